// Round 7
// baseline (48.832 us; speedup 1.0000x reference)
//
#include <hip/hip_runtime.h>

#define NB 8
#define NS 4
#define NN 8192
#define NM 50
#define K10 10
#define COST_THRESH 50.0f
#define LOSS_BLOCKS 256
#define NBUCK 1024
#define NSUB 2
#define MPB 2                  // gt's per block
#define CAP 256
#define TOTAL (NB * NS * NN)
#define TT 512                 // topk threads
#define ELEMS (NN / TT)        // 16 per thread

__device__ __forceinline__ bool lexless(float d1, int i1, float d2, int i2) {
  // matches jax.lax.top_k ordering on -dist: (dist asc, index asc)
  return (d1 < d2) || (d1 == d2 && i1 < i2);
}

// Clear assign + scalars only.
__global__ void __launch_bounds__(256) prep_kernel(
    int* __restrict__ assign, float* __restrict__ acc,
    int* __restrict__ bs_unm, int* __restrict__ done) {
  int i = blockIdx.x * blockDim.x + threadIdx.x;
  for (int j = i; j < TOTAL; j += gridDim.x * blockDim.x) assign[j] = -1;
  if (i == 0) { acc[0] = 0.0f; *done = 0; }
  if (i >= 64 && i < 64 + NB * NS) bs_unm[i - 64] = 0;
}

// One block per (b, s, m-pair): exact top-10 nearest preds for TWO gt's,
// sharing the pred loads and all phase overheads. Histogram-select on d^2.
__global__ void __launch_bounds__(TT) topk_kernel(
    const float* __restrict__ pred_boxes, const float* __restrict__ pred_scores,
    const float* __restrict__ gt_boxes, const int* __restrict__ n_gt,
    int* __restrict__ assign, float* __restrict__ per_gt_sum,
    int* __restrict__ bs_unm) {
  const int blk = blockIdx.x;           // bs * (NM/MPB) + mpair
  const int mp = blk % (NM / MPB);
  const int bs = blk / (NM / MPB);
  const int b = bs / NS;
  const int m0 = mp * MPB;
  const int t = threadIdx.x;
  const int wave = t >> 6;

  __shared__ int shist[MPB][NSUB][NBUCK];   // 16 KB
  __shared__ float scd[MPB][CAP];
  __shared__ int sci[MPB][CAP];
  __shared__ float sred[4][8];              // {min0,max0,min1,max1} x 8 waves
  __shared__ float sbb[MPB][2];             // bmin, scale per m
  __shared__ int scnt[MPB];
  __shared__ int sbucket[MPB];
  __shared__ float soutd[MPB][K10];
  __shared__ int souti[MPB][K10];

  for (int i = t; i < MPB * NSUB * NBUCK; i += TT) ((int*)shist)[i] = 0;
  if (t < MPB) { scnt[t] = 0; sbucket[t] = NBUCK - 2; }

  const float g0x = gt_boxes[(b * NM + m0) * 7 + 0];
  const float g0y = gt_boxes[(b * NM + m0) * 7 + 1];
  const float g0z = gt_boxes[(b * NM + m0) * 7 + 2];
  const float g1x = gt_boxes[(b * NM + m0 + 1) * 7 + 0];
  const float g1y = gt_boxes[(b * NM + m0 + 1) * 7 + 1];
  const float g1z = gt_boxes[(b * NM + m0 + 1) * 7 + 2];
  const int ngt = n_gt[b];

  // P1: shared loads, d^2 for both m's into registers; per-m min/max
  const float* pb = pred_boxes + (size_t)bs * NN * 7;
  float d2a[ELEMS], d2b[ELEMS];
  float lmin0 = INFINITY, lmax0 = 0.0f, lmin1 = INFINITY, lmax1 = 0.0f;
#pragma unroll
  for (int e = 0; e < ELEMS; e++) {
    int n = t + e * TT;
    float x = pb[n * 7 + 0];
    float y = pb[n * 7 + 1];
    float z = pb[n * 7 + 2];
    float dx = x - g0x, dy = y - g0y, dz = z - g0z;
    float d2 = dx * dx + dy * dy + dz * dz;
    d2a[e] = d2; lmin0 = fminf(lmin0, d2); lmax0 = fmaxf(lmax0, d2);
    dx = x - g1x; dy = y - g1y; dz = z - g1z;
    d2 = dx * dx + dy * dy + dz * dz;
    d2b[e] = d2; lmin1 = fminf(lmin1, d2); lmax1 = fmaxf(lmax1, d2);
  }
#pragma unroll
  for (int off = 32; off >= 1; off >>= 1) {
    lmin0 = fminf(lmin0, __shfl_down(lmin0, off));
    lmax0 = fmaxf(lmax0, __shfl_down(lmax0, off));
    lmin1 = fminf(lmin1, __shfl_down(lmin1, off));
    lmax1 = fmaxf(lmax1, __shfl_down(lmax1, off));
  }
  if ((t & 63) == 0) {
    sred[0][wave] = lmin0; sred[1][wave] = lmax0;
    sred[2][wave] = lmin1; sred[3][wave] = lmax1;
  }
  __syncthreads();
  if (t < MPB) {
    float bmin = INFINITY, bmax = 0.0f;
#pragma unroll
    for (int w = 0; w < TT / 64; w++) {
      bmin = fminf(bmin, sred[2 * t][w]);
      bmax = fmaxf(bmax, sred[2 * t + 1][w]);
    }
    sbb[t][0] = bmin;
    sbb[t][1] = (float)NBUCK / fmaxf(bmax - bmin, 1e-30f);
  }
  __syncthreads();
  const float bmin0 = sbb[0][0], scale0 = sbb[0][1];
  const float bmin1 = sbb[1][0], scale1 = sbb[1][1];

  // P2: both histograms (NSUB sub-copies each to cut contention)
  int* h0 = shist[0][wave & (NSUB - 1)];
  int* h1 = shist[1][wave & (NSUB - 1)];
#pragma unroll
  for (int e = 0; e < ELEMS; e++) {
    int b0 = min(NBUCK - 1, (int)((d2a[e] - bmin0) * scale0));
    atomicAdd(&h0[b0], 1);
    int b1 = min(NBUCK - 1, (int)((d2b[e] - bmin1) * scale1));
    atomicAdd(&h1[b1], 1);
  }
  __syncthreads();
  for (int i = t; i < MPB * NBUCK; i += TT) {
    int mm = i >> 10, ii = i & (NBUCK - 1);
    shist[mm][0][ii] += shist[mm][1][ii];
  }
  __syncthreads();

  // P3: wave 0 scans m0, wave 1 scans m1 (in parallel)
  if (t < MPB * 64) {
    int mw = t >> 6, lane = t & 63;
    int lsum = 0;
    for (int i = 0; i < NBUCK / 64; i++) lsum += shist[mw][0][lane * (NBUCK / 64) + i];
    int incl = lsum;
#pragma unroll
    for (int off = 1; off < 64; off <<= 1) {
      int v = __shfl_up(incl, off);
      if (lane >= off) incl += v;
    }
    int excl = incl - lsum;
    if (excl < K10 && incl >= K10) {
      int c = excl;
      for (int i = 0; i < NBUCK / 64; i++) {
        c += shist[mw][0][lane * (NBUCK / 64) + i];
        if (c >= K10) { sbucket[mw] = lane * (NBUCK / 64) + i; break; }
      }
    }
  }
  __syncthreads();
  // hi-edge of bucket j+1 plus half-bin margin (covers edge rounding + sqrt-ties)
  const float bound0 = bmin0 + ((float)(sbucket[0] + 2) + 0.5f) / scale0;
  const float bound1 = bmin1 + ((float)(sbucket[1] + 2) + 0.5f) / scale1;

  // P4: collect candidates (supersets of the exact top-10s)
#pragma unroll
  for (int e = 0; e < ELEMS; e++) {
    if (d2a[e] < bound0) {
      int p = atomicAdd(&scnt[0], 1);
      if (p < CAP) { scd[0][p] = d2a[e]; sci[0][p] = t + e * TT; }
    }
    if (d2b[e] < bound1) {
      int p = atomicAdd(&scnt[1], 1);
      if (p < CAP) { scd[1][p] = d2b[e]; sci[1][p] = t + e * TT; }
    }
  }
  __syncthreads();
  const int K0 = min(scnt[0], CAP);
  const int K1 = min(scnt[1], CAP);

  // P5: sqrt (matches reference dist exactly), exact rank by (d, idx)
  for (int c = t; c < K0; c += TT) scd[0][c] = sqrtf(scd[0][c]);
  for (int c = t; c < K1; c += TT) scd[1][c] = sqrtf(scd[1][c]);
  __syncthreads();
  for (int c = t; c < K0; c += TT) {
    float dc = scd[0][c]; int ic = sci[0][c];
    int rank = 0;
    for (int o = 0; o < K0; o++) rank += lexless(scd[0][o], sci[0][o], dc, ic) ? 1 : 0;
    if (rank < K10) { soutd[0][rank] = dc; souti[0][rank] = ic; }
  }
  for (int c = t; c < K1; c += TT) {
    float dc = scd[1][c]; int ic = sci[1][c];
    int rank = 0;
    for (int o = 0; o < K1; o++) rank += lexless(scd[1][o], sci[1][o], dc, ic) ? 1 : 0;
    if (rank < K10) { soutd[1][rank] = dc; souti[1][rank] = ic; }
  }
  __syncthreads();

  // epilogue: wave 0 handles m0, wave 1 handles m1
  if (t < MPB * 64) {
    int mw = t >> 6, lane = t & 63;
    int m = m0 + mw;
    bool valid = (m < ngt);
    bool pick = (lane < K10) && valid && (soutd[mw][lane] < COST_THRESH);
    if (pick) atomicMax(&assign[(size_t)bs * NN + souti[mw][lane]], m);
    bool matched = __any(pick);
    if (valid && !matched) {
      float a = 0.0f;
      if (lane < 5) a = expf(-0.5f * soutd[mw][lane]) * (1.0f - pred_scores[(size_t)bs * NN + souti[mw][lane]]);
#pragma unroll
      for (int off = 8; off >= 1; off >>= 1) a += __shfl_down(a, off);
      if (lane == 0) {
        atomicAdd(per_gt_sum, a * 0.2f);
        atomicOr(&bs_unm[bs], 1);
      }
    }
  }
}

// Fused loss reduction + final combine (last-block ticket).
__global__ void __launch_bounds__(256) loss_final_kernel(
    const float* __restrict__ pred_boxes, const float* __restrict__ pred_scores,
    const float* __restrict__ gt_boxes, const int* __restrict__ assign,
    float* __restrict__ partials, int* __restrict__ done,
    const float* __restrict__ acc, const int* __restrict__ bs_unm,
    const float* __restrict__ wc, const float* __restrict__ wo,
    const float* __restrict__ wu, float* __restrict__ out) {
  int tid = blockIdx.x * blockDim.x + threadIdx.x;
  float lc = 0.0f, spp = 0.0f, spn = 0.0f, np = 0.0f;
  for (int i = tid; i < TOTAL; i += gridDim.x * blockDim.x) {
    int a = assign[i];
    float x = pred_scores[i];
    if (a >= 0) {
      np += 1.0f;
      int b = i / (NS * NN);
      const float* gbp = &gt_boxes[(b * NM + a) * 7];
#pragma unroll
      for (int c = 0; c < 3; c++) {
        float diff = pred_boxes[(size_t)i * 7 + c] - gbp[c];
        float ad = fabsf(diff);
        lc += (ad < 1.0f) ? 0.5f * ad * ad : (ad - 0.5f);
      }
      spp += log1pf(expf(-fabsf(x))) + fmaxf(-x, 0.0f);  // softplus(-x)
    } else {
      spn += log1pf(expf(-fabsf(x))) + fmaxf(x, 0.0f);   // softplus(x)
    }
  }
#pragma unroll
  for (int off = 32; off >= 1; off >>= 1) {
    lc += __shfl_down(lc, off);
    spp += __shfl_down(spp, off);
    spn += __shfl_down(spn, off);
    np += __shfl_down(np, off);
  }
  __shared__ float red[4][4];
  __shared__ int s_last;
  int wave = threadIdx.x >> 6;
  if ((threadIdx.x & 63) == 0) {
    red[wave][0] = lc; red[wave][1] = spp; red[wave][2] = spn; red[wave][3] = np;
  }
  __syncthreads();
  if (threadIdx.x == 0) {
    float o0 = 0, o1 = 0, o2 = 0, o3 = 0;
#pragma unroll
    for (int w = 0; w < 4; w++) { o0 += red[w][0]; o1 += red[w][1]; o2 += red[w][2]; o3 += red[w][3]; }
    float* p = &partials[(size_t)blockIdx.x * 8];
    __hip_atomic_store(&p[0], o0, __ATOMIC_RELAXED, __HIP_MEMORY_SCOPE_AGENT);
    __hip_atomic_store(&p[1], o1, __ATOMIC_RELAXED, __HIP_MEMORY_SCOPE_AGENT);
    __hip_atomic_store(&p[2], o2, __ATOMIC_RELAXED, __HIP_MEMORY_SCOPE_AGENT);
    __hip_atomic_store(&p[3], o3, __ATOMIC_RELAXED, __HIP_MEMORY_SCOPE_AGENT);
    __threadfence();
    int ticket = __hip_atomic_fetch_add(done, 1, __ATOMIC_ACQ_REL, __HIP_MEMORY_SCOPE_AGENT);
    s_last = (ticket == gridDim.x - 1) ? 1 : 0;
  }
  __syncthreads();
  if (s_last) {
    __threadfence();
    const int t = threadIdx.x;
    float l0 = __hip_atomic_load(&partials[t * 8 + 0], __ATOMIC_RELAXED, __HIP_MEMORY_SCOPE_AGENT);
    float l1 = __hip_atomic_load(&partials[t * 8 + 1], __ATOMIC_RELAXED, __HIP_MEMORY_SCOPE_AGENT);
    float l2 = __hip_atomic_load(&partials[t * 8 + 2], __ATOMIC_RELAXED, __HIP_MEMORY_SCOPE_AGENT);
    float l3 = __hip_atomic_load(&partials[t * 8 + 3], __ATOMIC_RELAXED, __HIP_MEMORY_SCOPE_AGENT);
#pragma unroll
    for (int off = 32; off >= 1; off >>= 1) {
      l0 += __shfl_down(l0, off);
      l1 += __shfl_down(l1, off);
      l2 += __shfl_down(l2, off);
      l3 += __shfl_down(l3, off);
    }
    __shared__ float red2[4][4];
    if ((t & 63) == 0) {
      red2[t >> 6][0] = l0; red2[t >> 6][1] = l1; red2[t >> 6][2] = l2; red2[t >> 6][3] = l3;
    }
    __syncthreads();
    if (t == 0) {
      float o0 = 0, o1 = 0, o2 = 0, o3 = 0;
#pragma unroll
      for (int w = 0; w < 4; w++) { o0 += red2[w][0]; o1 += red2[w][1]; o2 += red2[w][2]; o3 += red2[w][3]; }
      int ne = 0;
      for (int i = 0; i < NB * NS; i++) ne += bs_unm[i];
      float n_pos = o3;
      float loss_center = o0 / fmaxf(n_pos * 3.0f, 1.0f);
      float n_neg = (float)TOTAL - n_pos;
      float pw = fminf(10.0f, n_neg / fmaxf(n_pos, 1.0f));
      float loss_obj = (pw * o1 + o2) / (float)TOTAL;
      float loss_unm = acc[0] / fmaxf((float)ne, 1.0f);
      out[0] = loss_center * wc[0] + loss_obj * wo[0] + loss_unm * wu[0];
    }
  }
}

extern "C" void kernel_launch(void* const* d_in, const int* in_sizes, int n_in,
                              void* d_out, int out_size, void* d_ws, size_t ws_size,
                              hipStream_t stream) {
  const float* pred_boxes = (const float*)d_in[0];
  // d_in[1] = pred_classes (unused), d_in[4] = gt_classes (unused), d_in[9] = epoch (unused)
  const float* pred_scores = (const float*)d_in[2];
  const float* gt_boxes = (const float*)d_in[3];
  const int* n_gt = (const int*)d_in[5];
  const float* wc = (const float*)d_in[6];
  const float* wo = (const float*)d_in[7];
  const float* wu = (const float*)d_in[8];
  float* out = (float*)d_out;

  char* ws = (char*)d_ws;
  int* assign = (int*)ws;                                   // TOTAL ints (1 MB)
  float* acc = (float*)(ws + (size_t)TOTAL * 4);            // acc[0] = per_gt_sum
  int* done = (int*)((char*)acc + 64);
  int* bs_unm = (int*)((char*)acc + 128);                   // NB*NS ints
  float* partials = (float*)((char*)acc + 512);             // LOSS_BLOCKS * 8 floats

  prep_kernel<<<256, 256, 0, stream>>>(assign, acc, bs_unm, done);
  topk_kernel<<<NB * NS * (NM / MPB), TT, 0, stream>>>(pred_boxes, pred_scores, gt_boxes,
                                                       n_gt, assign, &acc[0], bs_unm);
  loss_final_kernel<<<LOSS_BLOCKS, 256, 0, stream>>>(pred_boxes, pred_scores, gt_boxes, assign,
                                                     partials, done, acc, bs_unm, wc, wo, wu, out);
}